// Round 7
// baseline (854.023 us; speedup 1.0000x reference)
//
#include <hip/hip_runtime.h>

typedef unsigned short ushort_t;
typedef unsigned int uint_t;

static __device__ __forceinline__ ushort_t f2bf(float f) {
    uint_t u = __float_as_uint(f);
    uint_t r = (u + 0x7FFFu + ((u >> 16) & 1u)) >> 16;   // RNE
    return (ushort_t)r;
}
static __device__ __forceinline__ float bf2f(ushort_t u) {
    return __uint_as_float(((uint_t)u) << 16);
}
static __device__ __forceinline__ float bf2f_lo(uint_t u) {
    return __uint_as_float(u << 16);
}
static __device__ __forceinline__ float bf2f_hi(uint_t u) {
    return __uint_as_float(u & 0xffff0000u);
}
static __device__ __forceinline__ uint_t pack2(float lo, float hi) {
    return (uint_t)f2bf(lo) | ((uint_t)f2bf(hi) << 16);
}

#define RED16(p) { p += __shfl_xor(p,1); p += __shfl_xor(p,2); \
                   p += __shfl_xor(p,4); p += __shfl_xor(p,8); }

// ---------------- CSR build ----------------
__global__ __launch_bounds__(256) void k_count(
    const int* __restrict__ dst, int* __restrict__ deg, int E)
{
    int e = blockIdx.x * 256 + threadIdx.x;
    if (e < E) atomicAdd(&deg[dst[e]], 1);
}

__global__ __launch_bounds__(1024) void k_scanA(
    const int* __restrict__ deg, int* __restrict__ partial,
    int* __restrict__ bsum, int N)
{
    __shared__ int wsum[16];
    int tid = threadIdx.x, lane = tid & 63, wid = tid >> 6;
    int idx = blockIdx.x * 1024 + tid;
    int v = (idx < N) ? deg[idx] : 0;
    int x = v;
#pragma unroll
    for (int o = 1; o < 64; o <<= 1) {
        int t = __shfl_up(x, o, 64);
        if (lane >= o) x += t;
    }
    if (lane == 63) wsum[wid] = x;
    __syncthreads();
    if (wid == 0) {
        int s = (lane < 16) ? wsum[lane] : 0;
#pragma unroll
        for (int o = 1; o < 16; o <<= 1) {
            int t = __shfl_up(s, o, 64);
            if (lane >= o) s += t;
        }
        if (lane < 16) wsum[lane] = s;
    }
    __syncthreads();
    int woff = (wid > 0) ? wsum[wid - 1] : 0;
    if (idx < N) partial[idx] = woff + x - v;
    if (tid == 0) bsum[blockIdx.x] = wsum[15];
}

__global__ __launch_bounds__(256) void k_scanB(
    int* __restrict__ bsum, int nb, int* __restrict__ totalp)
{
    __shared__ int s[256];
    int tid = threadIdx.x;
    int v = (tid < nb) ? bsum[tid] : 0;
    s[tid] = v;
    __syncthreads();
#pragma unroll
    for (int off = 1; off < 256; off <<= 1) {
        int t = (tid >= off) ? s[tid - off] : 0;
        __syncthreads();
        s[tid] += t;
        __syncthreads();
    }
    if (tid < nb) bsum[tid] = s[tid] - v;
    if (tid == 0) totalp[0] = s[255];
}

__global__ __launch_bounds__(256) void k_scanC(
    int* __restrict__ offsets, const int* __restrict__ bsum,
    int* __restrict__ cursor, int N)
{
    int idx = blockIdx.x * 256 + threadIdx.x;
    if (idx >= N) return;
    int o = offsets[idx] + bsum[idx >> 10];
    offsets[idx] = o;
    cursor[idx] = o;
}

// entries[pos] = {src, eid, e.x, e.y}, grouped by dst
__global__ __launch_bounds__(256) void k_fill(
    const int* __restrict__ src, const int* __restrict__ dst,
    const float* __restrict__ ep, int* __restrict__ cursor,
    int4* __restrict__ entries, int E)
{
    int ei = blockIdx.x * 256 + threadIdx.x;
    if (ei >= E) return;
    int pos = atomicAdd(&cursor[dst[ei]], 1);
    float2 ev = *(const float2*)(ep + 2 * (size_t)ei);
    entries[pos] = make_int4(src[ei], ei, __float_as_int(ev.x), __float_as_int(ev.y));
}

// --------- shared epilogue: from x row (staged in xs) compute A,B tables ------
static __device__ __forceinline__ void epi_tables(
    float (*xs)[64], int wv, int lane, int li, int slot, int r, float o,
    const float* __restrict__ WAn, const float* __restrict__ bAn,
    const float* __restrict__ WBn,
    ushort_t* __restrict__ comb_out, ushort_t* __restrict__ B_out)
{
    xs[wv][lane] = o;
    float an = bAn[lane];
    float bn = 0.f;
#pragma unroll
    for (int k = 0; k < 64; k++) {
        float ok = xs[wv][k];
        an += ok * WAn[k * 64 + lane];
        bn += ok * WBn[k * 64 + lane];
    }
    B_out[(size_t)r * 64 + lane] = f2bf(bn);
    float a0 = __shfl(an, 4*li+0), a1 = __shfl(an, 4*li+1);
    float a2 = __shfl(an, 4*li+2), a3 = __shfl(an, 4*li+3);
    float g0 = __shfl(o,  4*li+0), g1 = __shfl(o,  4*li+1);
    float g2 = __shfl(o,  4*li+2), g3 = __shfl(o,  4*li+3);
    if (slot == 0) {
        int4 cw;
        cw.x = (int)pack2(a0, a1);
        cw.y = (int)pack2(a2, a3);
        cw.z = (int)pack2(g0, g1);
        cw.w = (int)pack2(g2, g3);
        *(int4*)(comb_out + (size_t)r * 128 + li * 8) = cw;
    }
}

// ------------- embed: h0 = h_in @ W + b; then head-0 comb/B tables ---------
__global__ __launch_bounds__(256) void k_embed_ab(
    const float* __restrict__ in, const float* __restrict__ W,
    const float* __restrict__ bias, float* __restrict__ hout,
    const float* __restrict__ WA, const float* __restrict__ bA,
    const float* __restrict__ WB,
    ushort_t* __restrict__ comb_out, ushort_t* __restrict__ B_out, int N)
{
    __shared__ float xs[4][64];
    const int wv   = threadIdx.x >> 6;
    const int lane = threadIdx.x & 63;
    const int li   = lane & 15;
    const int slot = lane >> 4;
    const int r    = blockIdx.x * 4 + wv;
    if (r >= N) return;
    xs[wv][lane] = in[(size_t)r * 64 + lane];
    float acc = bias[lane];
#pragma unroll
    for (int k = 0; k < 64; k++) acc += xs[wv][k] * W[k * 64 + lane];
    hout[(size_t)r * 64 + lane] = acc;
    epi_tables(xs, wv, lane, li, slot, r, acc, WA, bA, WB, comb_out, B_out);
}

// ------------- standalone tables (fallback when ws too small) -------------
__global__ __launch_bounds__(256) void k_tables(
    const float* __restrict__ h,
    const float* __restrict__ WA, const float* __restrict__ bA,
    const float* __restrict__ WB,
    ushort_t* __restrict__ comb_out, ushort_t* __restrict__ B_out, int N)
{
    __shared__ float xs[4][64];
    const int wv   = threadIdx.x >> 6;
    const int lane = threadIdx.x & 63;
    const int li   = lane & 15;
    const int slot = lane >> 4;
    const int r    = blockIdx.x * 4 + wv;
    if (r >= N) return;
    float o = h[(size_t)r * 64 + lane];
    epi_tables(xs, wv, lane, li, slot, r, o, WA, bA, WB, comb_out, B_out);
}

// ------------- fused: head i score (+ GIN layer i) (+ next head tables) ------
// ONE WAVE PER NODE. 4 edge-slots of 16 lanes; entries preloaded cooperatively;
// one 16B/lane combined {A|Hbf} gather per edge.
// MODE 0: score_csr = ; 1: score_csr += ; 2 (final): score_out[eid] = relu(score_csr+val)
template <int MODE, int HASGIN, int EPI>
__global__ __launch_bounds__(256) void k_fused(
    const float* __restrict__ h, float* __restrict__ hout,
    const ushort_t* __restrict__ comb, const ushort_t* __restrict__ Bm,
    const int4* __restrict__ entries, const int* __restrict__ offsets,
    float* __restrict__ score_csr, float* __restrict__ score_out,
    const float* __restrict__ Wc, const float* __restrict__ W2v,
    const float* __restrict__ b2p, const float* __restrict__ epsp,
    const float* __restrict__ W1, const float* __restrict__ b1,
    const float* __restrict__ s1, const float* __restrict__ sh1,
    const float* __restrict__ W2, const float* __restrict__ b2,
    const float* __restrict__ as_, const float* __restrict__ ash,
    const float* __restrict__ gs, const float* __restrict__ gsh,
    const float* __restrict__ WAn, const float* __restrict__ bAn,
    const float* __restrict__ WBn,
    ushort_t* __restrict__ comb_out, ushort_t* __restrict__ B_out, int N)
{
    __shared__ float xs[4][64];
    const int wv   = threadIdx.x >> 6;
    const int lane = threadIdx.x & 63;
    const int li   = lane & 15;
    const int slot = lane >> 4;
    const int r    = blockIdx.x * 4 + wv;
    if (r >= N) return;

    const float4 wc0 = *(const float4*)(Wc + li*4);
    const float4 wc1 = *(const float4*)(Wc + 64 + li*4);
    const float4 w2v = *(const float4*)(W2v + li*4);
    const float bb2 = b2p[0];
    ushort4 bu = *(const ushort4*)(Bm + (size_t)r * 64 + li*4);
    const float4 brow = make_float4(bf2f(bu.x), bf2f(bu.y), bf2f(bu.z), bf2f(bu.w));

    const int beg = offsets[r], end = offsets[r + 1];
    const int deg = end - beg;
    float4 acc = make_float4(0.f, 0.f, 0.f, 0.f);

    for (int base = 0; base < deg; base += 64) {
        const int nb = min(64, deg - base);
        int4 ent = make_int4(0, 0, 0, 0);
        if (lane < nb) ent = entries[beg + base + lane];

        int j0 = 0;
        // dual-round: 8 edges, gathers issued before consumption (full exec)
        for (; j0 + 8 <= nb; j0 += 8) {
            const int ja = j0 + slot;
            const int jb = j0 + 4 + slot;
            int   sa = __shfl(ent.x, ja);
            int   sb = __shfl(ent.x, jb);
            int   ea = __shfl(ent.y, ja);
            int   eb = __shfl(ent.y, jb);
            float xa = __int_as_float(__shfl(ent.z, ja));
            float xb = __int_as_float(__shfl(ent.z, jb));
            float ya = __int_as_float(__shfl(ent.w, ja));
            float yb = __int_as_float(__shfl(ent.w, jb));
            int4 ca = *(const int4*)(comb + (size_t)sa * 128 + li * 8);
            int4 cb = *(const int4*)(comb + (size_t)sb * 128 + li * 8);
            if (HASGIN) {
                acc.x += bf2f_lo(ca.z) + bf2f_lo(cb.z);
                acc.y += bf2f_hi(ca.z) + bf2f_hi(cb.z);
                acc.z += bf2f_lo(ca.w) + bf2f_lo(cb.w);
                acc.w += bf2f_hi(ca.w) + bf2f_hi(cb.w);
            }
            float z0 = bf2f_lo(ca.x) + brow.x + xa*wc0.x + ya*wc1.x; z0 = fmaxf(z0, 0.f);
            float z1 = bf2f_hi(ca.x) + brow.y + xa*wc0.y + ya*wc1.y; z1 = fmaxf(z1, 0.f);
            float z2 = bf2f_lo(ca.y) + brow.z + xa*wc0.z + ya*wc1.z; z2 = fmaxf(z2, 0.f);
            float z3 = bf2f_hi(ca.y) + brow.w + xa*wc0.w + ya*wc1.w; z3 = fmaxf(z3, 0.f);
            float pa = z0*w2v.x + z1*w2v.y + z2*w2v.z + z3*w2v.w;
            z0 = bf2f_lo(cb.x) + brow.x + xb*wc0.x + yb*wc1.x; z0 = fmaxf(z0, 0.f);
            z1 = bf2f_hi(cb.x) + brow.y + xb*wc0.y + yb*wc1.y; z1 = fmaxf(z1, 0.f);
            z2 = bf2f_lo(cb.y) + brow.z + xb*wc0.z + yb*wc1.z; z2 = fmaxf(z2, 0.f);
            z3 = bf2f_hi(cb.y) + brow.w + xb*wc0.w + yb*wc1.w; z3 = fmaxf(z3, 0.f);
            float pb = z0*w2v.x + z1*w2v.y + z2*w2v.z + z3*w2v.w;
            RED16(pa) RED16(pb)
            if (li == 0) {
                int ka = beg + base + ja;
                int kb = beg + base + jb;
                if (MODE == 0) {
                    score_csr[ka] = pa + bb2;
                    score_csr[kb] = pb + bb2;
                } else if (MODE == 1) {
                    score_csr[ka] += pa + bb2;
                    score_csr[kb] += pb + bb2;
                } else {
                    score_out[ea] = fmaxf(score_csr[ka] + pa + bb2, 0.f);
                    score_out[eb] = fmaxf(score_csr[kb] + pb + bb2, 0.f);
                }
            }
        }
        // tail rounds — FULL-EXEC shfls: ds_bpermute from an EXEC-inactive
        // source lane is undefined, and source lane j may live in a slot whose
        // predicate is false. Clamp the index, predicate only side effects.
        for (; j0 < nb; j0 += 4) {
            const int j  = j0 + slot;
            const bool ok = (j < nb);
            const int jc = ok ? j : (nb - 1);
            int   sa = __shfl(ent.x, jc);
            int   ea = __shfl(ent.y, jc);
            float xa = __int_as_float(__shfl(ent.z, jc));
            float ya = __int_as_float(__shfl(ent.w, jc));
            int4 ca = *(const int4*)(comb + (size_t)sa * 128 + li * 8);
            if (HASGIN && ok) {
                acc.x += bf2f_lo(ca.z); acc.y += bf2f_hi(ca.z);
                acc.z += bf2f_lo(ca.w); acc.w += bf2f_hi(ca.w);
            }
            float z0 = bf2f_lo(ca.x) + brow.x + xa*wc0.x + ya*wc1.x; z0 = fmaxf(z0, 0.f);
            float z1 = bf2f_hi(ca.x) + brow.y + xa*wc0.y + ya*wc1.y; z1 = fmaxf(z1, 0.f);
            float z2 = bf2f_lo(ca.y) + brow.z + xa*wc0.z + ya*wc1.z; z2 = fmaxf(z2, 0.f);
            float z3 = bf2f_hi(ca.y) + brow.w + xa*wc0.w + ya*wc1.w; z3 = fmaxf(z3, 0.f);
            float p = z0*w2v.x + z1*w2v.y + z2*w2v.z + z3*w2v.w;
            RED16(p)
            if (li == 0 && ok) {
                int ka = beg + base + j;
                if (MODE == 0)      score_csr[ka] = p + bb2;
                else if (MODE == 1) score_csr[ka] += p + bb2;
                else score_out[ea] = fmaxf(score_csr[ka] + p + bb2, 0.f);
            }
        }
    }

    if (!HASGIN) return;

    // cross-slot reduce of aggregation (full exec)
    acc.x += __shfl_xor(acc.x, 16); acc.x += __shfl_xor(acc.x, 32);
    acc.y += __shfl_xor(acc.y, 16); acc.y += __shfl_xor(acc.y, 32);
    acc.z += __shfl_xor(acc.z, 16); acc.z += __shfl_xor(acc.z, 32);
    acc.w += __shfl_xor(acc.w, 16); acc.w += __shfl_xor(acc.w, 32);
    if (slot == 0) *(float4*)(&xs[wv][li * 4]) = acc;

    const float epsv = 1.0f + epsp[0];
    const float hself = h[(size_t)r * 64 + lane];
    float x = epsv * hself + xs[wv][lane];
    xs[wv][lane] = x;

    float t = b1[lane];
#pragma unroll
    for (int k = 0; k < 64; k++) t += xs[wv][k] * W1[k * 64 + lane];
    t = fmaxf(t * s1[lane] + sh1[lane], 0.f);
    xs[wv][lane] = t;

    float u = b2[lane];
#pragma unroll
    for (int k = 0; k < 64; k++) u += xs[wv][k] * W2[k * 64 + lane];
    u = fmaxf(u * as_[lane] + ash[lane], 0.f);
    u = fmaxf(u * gs[lane] + gsh[lane], 0.f);

    float o = hself + u;
    hout[(size_t)r * 64 + lane] = o;

    if (EPI)
        epi_tables(xs, wv, lane, li, slot, r, o, WAn, bAn, WBn, comb_out, B_out);
}

extern "C" void kernel_launch(void* const* d_in, const int* in_sizes, int n_in,
                              void* d_out, int out_size, void* d_ws, size_t ws_size,
                              hipStream_t stream) {
    const float* h_in  = (const float*)d_in[0];
    const float* e     = (const float*)d_in[1];
    const int*   src   = (const int*)d_in[2];
    const int*   dst   = (const int*)d_in[3];
    const float* emb_W = (const float*)d_in[4];
    const float* emb_b = (const float*)d_in[5];
    const float* eps   = (const float*)d_in[6];
    const float* mW1   = (const float*)d_in[7];
    const float* mb1   = (const float*)d_in[8];
    const float* mbs   = (const float*)d_in[9];
    const float* mbsh  = (const float*)d_in[10];
    const float* mW2   = (const float*)d_in[11];
    const float* mb2   = (const float*)d_in[12];
    const float* as_   = (const float*)d_in[13];
    const float* ash   = (const float*)d_in[14];
    const float* gs    = (const float*)d_in[15];
    const float* gsh   = (const float*)d_in[16];
    const float* pW1   = (const float*)d_in[17];
    const float* pb1   = (const float*)d_in[18];
    const float* pW2   = (const float*)d_in[19];
    const float* pb2   = (const float*)d_in[20];

    const int N  = in_sizes[0] / 64;
    const int E  = in_sizes[2];
    const int Lr = in_sizes[6];
    const size_t nrow = (size_t)N * 64;

    float* score = (float*)d_out;

    char* wp = (char*)d_ws;
    auto take = [&](size_t b) -> char* {
        char* p = wp; wp += (b + 255) & ~(size_t)255; return p;
    };
    float*    h0        = (float*)take(nrow * 4);
    float*    h1        = (float*)take(nrow * 4);
    ushort_t* comb0     = (ushort_t*)take(nrow * 4);   // [N][128] ushort = 256B/node
    ushort_t* B0        = (ushort_t*)take(nrow * 2);
    int4*     entries   = (int4*)take((size_t)E * 16);
    float*    score_csr = (float*)take((size_t)E * 4);
    int*      offsets   = (int*)take((size_t)(N + 1) * 4);
    int*      cursor    = (int*)take((size_t)N * 4);
    int*      bsum      = (int*)take(1024);
    size_t need_base = (size_t)(wp - (char*)d_ws);
    ushort_t* comb1     = (ushort_t*)take(nrow * 4);
    ushort_t* B1        = (ushort_t*)take(nrow * 2);
    size_t need_epi = (size_t)(wp - (char*)d_ws);
    (void)need_base;

    const bool use_epi = ws_size >= need_epi;

    const int fusedBlocks = (N + 3) / 4;
    const int edgeGrid    = (E + 255) / 256;
    const int nb          = (N + 1023) / 1024;

    // ---- CSR build ----
    hipMemsetAsync(cursor, 0, (size_t)N * sizeof(int), stream);
    k_count<<<edgeGrid, 256, 0, stream>>>(dst, cursor, E);
    k_scanA<<<nb, 1024, 0, stream>>>(cursor, offsets, bsum, N);
    k_scanB<<<1, 256, 0, stream>>>(bsum, nb, offsets + N);
    k_scanC<<<(N + 255) / 256, 256, 0, stream>>>(offsets, bsum, cursor, N);
    k_fill<<<edgeGrid, 256, 0, stream>>>(src, dst, e, cursor, entries, E);

    // ---- embed + head-0 tables ----
    k_embed_ab<<<fusedBlocks, 256, 0, stream>>>(
        h_in, emb_W, emb_b, h0, pW1, pb1, pW1 + 64 * 64, comb0, B0, N);

    float* hcur = h0;       float* hnext = h1;
    ushort_t* Ccur = comb0; ushort_t* Cnxt = use_epi ? comb1 : comb0;
    ushort_t* Bcur = B0;    ushort_t* Bnxt = use_epi ? B1 : B0;

    for (int i = 0; i < Lr; i++) {
        const float* pw  = pW1 + (size_t)i * 130 * 64;
        const float* Wc  = pw + 128 * 64;
        const float* w2  = pW2 + (size_t)i * 64;
        const float* b2  = pb2 + i;
        const float* pwn = pW1 + (size_t)(i + 1) * 130 * 64;
        const float* gW1 = mW1 + (size_t)i * 64 * 64;
        const float* gW2 = mW2 + (size_t)i * 64 * 64;

        if (use_epi) {
            if (i == 0)
                k_fused<0,1,1><<<fusedBlocks, 256, 0, stream>>>(
                    hcur, hnext, Ccur, Bcur, entries, offsets, score_csr, nullptr,
                    Wc, w2, b2, eps + i,
                    gW1, mb1 + i*64, mbs + i*64, mbsh + i*64, gW2, mb2 + i*64,
                    as_ + i*64, ash + i*64, gs + i*64, gsh + i*64,
                    pwn, pb1 + (i+1)*64, pwn + 64*64, Cnxt, Bnxt, N);
            else
                k_fused<1,1,1><<<fusedBlocks, 256, 0, stream>>>(
                    hcur, hnext, Ccur, Bcur, entries, offsets, score_csr, nullptr,
                    Wc, w2, b2, eps + i,
                    gW1, mb1 + i*64, mbs + i*64, mbsh + i*64, gW2, mb2 + i*64,
                    as_ + i*64, ash + i*64, gs + i*64, gsh + i*64,
                    pwn, pb1 + (i+1)*64, pwn + 64*64, Cnxt, Bnxt, N);
            { ushort_t* t = Ccur; Ccur = Cnxt; Cnxt = t; }
            { ushort_t* t = Bcur; Bcur = Bnxt; Bnxt = t; }
        } else {
            if (i == 0)
                k_fused<0,1,0><<<fusedBlocks, 256, 0, stream>>>(
                    hcur, hnext, Ccur, Bcur, entries, offsets, score_csr, nullptr,
                    Wc, w2, b2, eps + i,
                    gW1, mb1 + i*64, mbs + i*64, mbsh + i*64, gW2, mb2 + i*64,
                    as_ + i*64, ash + i*64, gs + i*64, gsh + i*64,
                    nullptr, nullptr, nullptr, nullptr, nullptr, N);
            else
                k_fused<1,1,0><<<fusedBlocks, 256, 0, stream>>>(
                    hcur, hnext, Ccur, Bcur, entries, offsets, score_csr, nullptr,
                    Wc, w2, b2, eps + i,
                    gW1, mb1 + i*64, mbs + i*64, mbsh + i*64, gW2, mb2 + i*64,
                    as_ + i*64, ash + i*64, gs + i*64, gsh + i*64,
                    nullptr, nullptr, nullptr, nullptr, nullptr, N);
            k_tables<<<fusedBlocks, 256, 0, stream>>>(
                hnext, pwn, pb1 + (i+1)*64, pwn + 64*64, Ccur, Bcur, N);
        }
        { float* t = hcur; hcur = hnext; hnext = t; }
    }

    // ---- final head: score_out[eid] = relu(score_csr + pred) ----
    {
        const float* pw = pW1 + (size_t)Lr * 130 * 64;
        const float* Wc = pw + 128 * 64;
        const float* w2 = pW2 + (size_t)Lr * 64;
        const float* b2 = pb2 + Lr;
        k_fused<2,0,0><<<fusedBlocks, 256, 0, stream>>>(
            hcur, nullptr, Ccur, Bcur, entries, offsets, score_csr, score,
            Wc, w2, b2, nullptr,
            nullptr, nullptr, nullptr, nullptr, nullptr, nullptr,
            nullptr, nullptr, nullptr, nullptr,
            nullptr, nullptr, nullptr, nullptr, nullptr, N);
    }
}